// Round 9
// baseline (370.351 us; speedup 1.0000x reference)
//
#include <hip/hip_runtime.h>

#define N_   64
#define C_   512
#define HW_  1024
#define SC_  64              // spatial chunk per fused block
#define NSC_ (HW_ / SC_)     // 16 chunks -> grid = 64*16 = 1024 blocks

typedef float f4v __attribute__((ext_vector_type(4)));

// ---------------------------------------------------------------------------
// K1: gap[n*C+c] = mean over 1024 contiguous spatial elements.
// Normal (caching) loads: warms L3 with x for the fused pass.
// ---------------------------------------------------------------------------
__global__ __launch_bounds__(256) void gap_kernel(const float* __restrict__ x,
                                                  float* __restrict__ gap) {
    int wave = threadIdx.x >> 6;
    int lane = threadIdx.x & 63;
    int row  = blockIdx.x * 4 + wave;                 // row = n*C + c
    const float4* xr = (const float4*)(x + (size_t)row * HW_);
    float s = 0.f;
    #pragma unroll
    for (int j = 0; j < 4; ++j) {
        float4 v = xr[lane + j * 64];
        s += v.x + v.y + v.z + v.w;
    }
    #pragma unroll
    for (int off = 32; off > 0; off >>= 1) s += __shfl_down(s, off, 64);
    if (lane == 0) gap[row] = s * (1.0f / 1024.0f);
}

// ---------------------------------------------------------------------------
// K2: fused qk + moments + apply. Block = (n, s-chunk of 64), 256 threads.
// Thread (sq4 = tid&15, cg4 = tid>>4) owns s-quad 4*sq4 and rows cg4+16j.
// Phase B: float4 moments; x stashed in 32 f4v REGISTERS (~128 VGPR).
//          Cross-c reduce: shfl_xor(16,32) butterfly within wave (merges the
//          wave's 4 cg4 groups), then cross-wave via mpart LDS.
// Phase C: apply reuses the register stash -> NO x re-read at all.
// __launch_bounds__(256,2): allow ~190 VGPR (8 waves/CU, 2 blocks/CU).
// mfin reduce: full 7*64 coverage via strided loop (round-8 bugfix kept).
// ---------------------------------------------------------------------------
__global__ __launch_bounds__(256, 2) void fused_kernel(const float* __restrict__ x,
    const float* __restrict__ gap,
    const float* __restrict__ wq, const float* __restrict__ bq,
    const float* __restrict__ wk, const float* __restrict__ bk,
    float* __restrict__ out) {
    __shared__ float g[C_ + 2];
    __shared__ float qs[C_], ks[C_];
    __shared__ float red[4][12];
    __shared__ alignas(16) float mpart[4][7][SC_];
    __shared__ alignas(16) float mfin[7][SC_];
    __shared__ float invf[8];
    __shared__ float alpha_s;

    int n     = blockIdx.x >> 4;          // / NSC_
    int chunk = blockIdx.x & (NSC_ - 1);
    int tid   = threadIdx.x;
    int lane  = tid & 63;
    int wv    = tid >> 6;
    int s0    = chunk * SC_;
    int sq4   = tid & 15;                 // s-quad (4 consecutive s)
    int cg4   = tid >> 4;                 // row-group (0..15)

    if (tid == 0) {
        g[0] = 0.f; g[C_ + 1] = 0.f;
        invf[0] = 1.f;        invf[1] = 1.f;         invf[2] = 0.5f;
        invf[3] = 1.f / 6.f;  invf[4] = 1.f / 24.f;  invf[5] = 1.f / 120.f;
        invf[6] = 1.f / 720.f;
    }
    g[1 + tid]       = gap[n * C_ + tid];
    g[1 + tid + 256] = gap[n * C_ + tid + 256];
    __syncthreads();

    // ---- phase A: q, k, power sums, alpha = 1/S ----
    float w0 = wq[0], w1 = wq[1], w2 = wq[2], b0 = bq[0];
    float u0 = wk[0], u1 = wk[1], u2 = wk[2], c0 = bk[0];

    float sq[6] = {0, 0, 0, 0, 0, 0};
    float sk[6] = {0, 0, 0, 0, 0, 0};
    #pragma unroll
    for (int j = 0; j < 2; ++j) {
        int c = tid + j * 256;
        float qv = fmaxf(0.f, w0 * g[c] + w1 * g[c + 1] + w2 * g[c + 2] + b0);
        float kv = fmaxf(0.f, u0 * g[c] + u1 * g[c + 1] + u2 * g[c + 2] + c0);
        qs[c] = qv; ks[c] = kv;
        float pq = qv, pk = kv;
        #pragma unroll
        for (int t = 0; t < 6; ++t) { sq[t] += pq; pq *= qv; sk[t] += pk; pk *= kv; }
    }
    {
        float vals[12];
        #pragma unroll
        for (int t = 0; t < 6; ++t) { vals[t] = sq[t]; vals[6 + t] = sk[t]; }
        #pragma unroll
        for (int j = 0; j < 12; ++j) {
            float v = vals[j];
            #pragma unroll
            for (int off = 32; off > 0; off >>= 1) v += __shfl_down(v, off, 64);
            if (lane == 0) red[wv][j] = v;
        }
    }
    __syncthreads();
    if (tid == 0) {
        const float ifct[6] = {1.f, 0.5f, 1.f / 6.f, 1.f / 24.f,
                               1.f / 120.f, 1.f / 720.f};
        float S = (float)C_ * (float)C_;
        #pragma unroll
        for (int t = 0; t < 6; ++t) {
            float tq = 0.f, tk = 0.f;
            #pragma unroll
            for (int w = 0; w < 4; ++w) { tq += red[w][t]; tk += red[w][6 + t]; }
            S += tq * tk * ifct[t];
        }
        alpha_s = 1.0f / S;
    }
    // alpha_s visibility covered by the barrier after phase B.

    // ---- phase B: float4 moments over rows cg4+16j; stash x in regs ----
    f4v xs[32];
    {
        const f4v* xq = (const f4v*)(x + ((size_t)n * C_ + cg4) * HW_
                                     + s0 + 4 * sq4);
        f4v m0 = (f4v)0.f, m1 = m0, m2 = m0, m3 = m0, m4 = m0, m5 = m0, m6 = m0;
        #pragma unroll
        for (int j = 0; j < 32; ++j) {
            f4v xv = xq[(size_t)(16 * j) * (HW_ / 4)];
            xs[j] = xv;
            float kc = ks[cg4 + 16 * j];
            f4v p = xv;
            m0 += p; p *= kc;
            m1 += p; p *= kc;
            m2 += p; p *= kc;
            m3 += p; p *= kc;
            m4 += p; p *= kc;
            m5 += p; p *= kc;
            m6 += p;
        }
        // butterfly over the wave's 4 cg4 groups (lane bits 4,5 — sq4 bits
        // 0..3 preserved, so partners share the same s-quad).
        f4v mm[7] = {m0, m1, m2, m3, m4, m5, m6};
        #pragma unroll
        for (int t = 0; t < 7; ++t) {
            f4v v = mm[t];
            v.x += __shfl_xor(v.x, 16, 64); v.y += __shfl_xor(v.y, 16, 64);
            v.z += __shfl_xor(v.z, 16, 64); v.w += __shfl_xor(v.w, 16, 64);
            v.x += __shfl_xor(v.x, 32, 64); v.y += __shfl_xor(v.y, 32, 64);
            v.z += __shfl_xor(v.z, 32, 64); v.w += __shfl_xor(v.w, 32, 64);
            if (lane < 16) *(f4v*)&mpart[wv][t][4 * lane] = v;  // 16B-aligned
        }
    }
    __syncthreads();

    // ---- mfin reduce: ALL 7*64 pairs via strided loop (256 threads) ----
    #pragma unroll
    for (int r = 0; r < 7 * SC_; r += 256) {
        int idx = r + tid;
        if (idx < 7 * SC_) {
            int t = idx >> 6, l = idx & 63;
            float v = mpart[0][t][l] + mpart[1][t][l] + mpart[2][t][l]
                    + mpart[3][t][l];
            mfin[t][l] = v * alpha_s * invf[t];
        }
    }
    __syncthreads();

    // ---- phase C: apply from the register stash (no x re-read) ----
    {
        int b = 4 * sq4;
        f4v a0 = {mfin[0][b], mfin[0][b+1], mfin[0][b+2], mfin[0][b+3]};
        f4v a1 = {mfin[1][b], mfin[1][b+1], mfin[1][b+2], mfin[1][b+3]};
        f4v a2 = {mfin[2][b], mfin[2][b+1], mfin[2][b+2], mfin[2][b+3]};
        f4v a3 = {mfin[3][b], mfin[3][b+1], mfin[3][b+2], mfin[3][b+3]};
        f4v a4 = {mfin[4][b], mfin[4][b+1], mfin[4][b+2], mfin[4][b+3]};
        f4v a5 = {mfin[5][b], mfin[5][b+1], mfin[5][b+2], mfin[5][b+3]};
        f4v a6 = {mfin[6][b], mfin[6][b+1], mfin[6][b+2], mfin[6][b+3]};
        f4v* og = (f4v*)(out + ((size_t)n * C_ + cg4) * HW_ + s0 + 4 * sq4);
        #pragma unroll
        for (int j = 0; j < 32; ++j) {
            float q = qs[cg4 + 16 * j];
            f4v att = a6 * q + a5;
            att = att * q + a4;
            att = att * q + a3;
            att = att * q + a2;
            att = att * q + a1;
            att = att * q + a0;
            f4v res = xs[j] * att;
            __builtin_nontemporal_store(res, og + (size_t)(16 * j) * (HW_ / 4));
        }
    }
}

// ---------------------------------------------------------------------------
extern "C" void kernel_launch(void* const* d_in, const int* in_sizes, int n_in,
                              void* d_out, int out_size, void* d_ws, size_t ws_size,
                              hipStream_t stream) {
    const float* x  = (const float*)d_in[0];
    const float* wq = (const float*)d_in[1];
    const float* bq = (const float*)d_in[2];
    const float* wk = (const float*)d_in[3];
    const float* bk = (const float*)d_in[4];
    float* out = (float*)d_out;

    float* gap = (float*)d_ws;            // N*C = 32768 floats

    gap_kernel  <<<dim3(N_ * C_ / 4), dim3(256), 0, stream>>>(x, gap);
    fused_kernel<<<dim3(N_ * NSC_),   dim3(256), 0, stream>>>(x, gap, wq, bq,
                                                              wk, bk, out);
}